// Round 1
// 1032.002 us; speedup vs baseline: 1.0368x; 1.0368x over previous
//
#include <hip/hip_runtime.h>
#include <hip/hip_bf16.h>
#include <math.h>

#define BB 4096
#define TT 200
#define EE 64

// ws float layout:
//  [0,5120)          WkC = W1[64:128]-W1[128:192]   (64x80)
//  [5120,10240)      WqC = W1[0:64]+W1[128:192]     (64x80)
//  [10240,337920)    qW  = targets@WqC + b1         (B x 80)
//  [337920,1157120)  logits [T][B]
//  [1157120,1976320) scores [T][B]
//  -- big-ws path only --
//  [1976320,3614720) xg   [T][B] float2 {x.Wu1, x.Wr1}
//  [3614720,56043520) xc  [T][B][64] = x@Wc1 + bc
#define OFF_XG 1976320
#define OFF_XC 3614720
#define WS_NEED_BYTES ((size_t)(OFF_XC + (size_t)BB * TT * 64) * 4)

__device__ __forceinline__ float lane_bcast(float v, int l) {
    return __int_as_float(__builtin_amdgcn_readlane(__float_as_int(v), l));
}

__global__ __launch_bounds__(256) void prep_kernel(const float* __restrict__ W1,
                                                   float* __restrict__ ws) {
    int idx = blockIdx.x * 256 + threadIdx.x;   // i*80+j, i<64
    if (idx >= 64 * 80) return;
    float wa = W1[idx];
    float wb = W1[64 * 80 + idx];
    float wc = W1[128 * 80 + idx];
    ws[idx]        = wb - wc;   // WkC
    ws[5120 + idx] = wa + wc;   // WqC
}

__global__ __launch_bounds__(256) void qw_kernel(const float* __restrict__ targets,
                                                 const float* __restrict__ b1,
                                                 const float* __restrict__ ws,
                                                 float* __restrict__ qW) {
    int idx = blockIdx.x * 256 + threadIdx.x;   // b*80+j
    int b = idx / 80;
    int j = idx - b * 80;
    const float* q  = targets + (size_t)b * 64;
    const float* Wq = ws + 5120;
    float s = b1[j];
#pragma unroll
    for (int i = 0; i < 64; i++) s = fmaf(q[i], Wq[i * 80 + j], s);
    qW[idx] = s;
}

// one thread per (b,t): logit via restructured MLP (LDS-broadcast weights).
// Additionally (big-ws path) emits the AUGRU gate x-dots xg = {x.Wu1, x.Wr1}
// since this thread already holds the x row in registers.
__global__ __launch_bounds__(256) void mlp_kernel(
    const float* __restrict__ gru, const float* __restrict__ targets,
    const float* __restrict__ W1, const float* __restrict__ W2,
    const float* __restrict__ b2, const float* __restrict__ Wf,
    const float* __restrict__ bf, const float* __restrict__ Wu,
    const float* __restrict__ Wr, const float* __restrict__ ws,
    float* __restrict__ logits, float* __restrict__ xg) {
    __shared__ float4 sWk[1280];   // [64][20 quads]
    __shared__ float4 sWp[1280];
    const float4* WkC = (const float4*)ws;              // 5120 floats
    const float4* Wp  = (const float4*)(W1 + 192 * 80); // last 64 rows of W1
    for (int i = threadIdx.x; i < 1280; i += 256) {
        sWk[i] = WkC[i];
        sWp[i] = Wp[i];
    }
    __syncthreads();

    int idx = blockIdx.x * 256 + threadIdx.x;   // exactly B*T threads
    int b = idx / 200;
    int t = idx - b * 200;
    const float4* kp  = (const float4*)(gru + ((size_t)b * 200 + t) * 64);
    const float4* qp  = (const float4*)(targets + (size_t)b * 64);
    const float4* qWv = (const float4*)(ws + 10240 + (size_t)b * 80);
    const float4* Wuq = (const float4*)Wu;   // uniform -> s_load
    const float4* Wrq = (const float4*)Wr;

    float4 h1[20];
#pragma unroll
    for (int j = 0; j < 20; j++) h1[j] = qWv[j];

    float4 xum = {0.f, 0.f, 0.f, 0.f};
    float4 xrm = {0.f, 0.f, 0.f, 0.f};

    for (int i4 = 0; i4 < 16; i4++) {
        float4 kv = kp[i4];
        float4 qv = qp[i4];
        float4 wu = Wuq[i4];
        float4 wr = Wrq[i4];
        xum.x = fmaf(kv.x, wu.x, xum.x); xum.y = fmaf(kv.y, wu.y, xum.y);
        xum.z = fmaf(kv.z, wu.z, xum.z); xum.w = fmaf(kv.w, wu.w, xum.w);
        xrm.x = fmaf(kv.x, wr.x, xrm.x); xrm.y = fmaf(kv.y, wr.y, xrm.y);
        xrm.z = fmaf(kv.z, wr.z, xrm.z); xrm.w = fmaf(kv.w, wr.w, xrm.w);
        float kk[4] = {kv.x, kv.y, kv.z, kv.w};
        float pp[4] = {qv.x * kv.x, qv.y * kv.y, qv.z * kv.z, qv.w * kv.w};
#pragma unroll
        for (int u = 0; u < 4; u++) {
            const float4* wk = &sWk[(i4 * 4 + u) * 20];
            const float4* wp = &sWp[(i4 * 4 + u) * 20];
            float ki = kk[u], pi = pp[u];
#pragma unroll
            for (int j = 0; j < 20; j++) {
                float4 a = wk[j], c = wp[j];
                h1[j].x = fmaf(ki, a.x, fmaf(pi, c.x, h1[j].x));
                h1[j].y = fmaf(ki, a.y, fmaf(pi, c.y, h1[j].y));
                h1[j].z = fmaf(ki, a.z, fmaf(pi, c.z, h1[j].z));
                h1[j].w = fmaf(ki, a.w, fmaf(pi, c.w, h1[j].w));
            }
        }
    }
    if (xg) {
        float xu = (xum.x + xum.y) + (xum.z + xum.w);
        float xr = (xrm.x + xrm.y) + (xrm.z + xrm.w);
        ((float2*)xg)[(size_t)t * BB + b] = make_float2(xu, xr);
    }
    // layer 2: 80 -> 40
    float4 h2[10];
    const float4* b2v = (const float4*)b2;
    const float4* W2v = (const float4*)W2;   // [80][10 quads]
#pragma unroll
    for (int j = 0; j < 10; j++) h2[j] = b2v[j];
#pragma unroll
    for (int iq = 0; iq < 20; iq++) {
        float4 hv = h1[iq];
        float hs[4] = {hv.x, hv.y, hv.z, hv.w};
#pragma unroll
        for (int u = 0; u < 4; u++) {
            float v = hs[u];
            const float4* wr2 = W2v + (iq * 4 + u) * 10;
#pragma unroll
            for (int j = 0; j < 10; j++) {
                float4 w = wr2[j];
                h2[j].x = fmaf(v, w.x, h2[j].x);
                h2[j].y = fmaf(v, w.y, h2[j].y);
                h2[j].z = fmaf(v, w.z, h2[j].z);
                h2[j].w = fmaf(v, w.w, h2[j].w);
            }
        }
    }
    // final: 40 -> 1
    const float4* Wfv = (const float4*)Wf;
    float lg = bf[0];
#pragma unroll
    for (int j = 0; j < 10; j++) {
        float4 w = Wfv[j];
        lg = fmaf(h2[j].x, w.x, lg);
        lg = fmaf(h2[j].y, w.y, lg);
        lg = fmaf(h2[j].z, w.z, lg);
        lg = fmaf(h2[j].w, w.w, lg);
    }
    if (lg == 0.0f) lg = -INFINITY;
    logits[(size_t)t * BB + b] = lg;
}

// softmax over batch dim for each t; scores stored [T][B] (coalesced)
__global__ __launch_bounds__(256) void softmax_kernel(const float* __restrict__ logits,
                                                      float* __restrict__ scores) {
    int t = blockIdx.x;
    int tid = threadIdx.x;
    const float* L = logits + (size_t)t * BB;
    float v[16];
#pragma unroll
    for (int i = 0; i < 16; i++) {
        float x = L[tid + i * 256];
        v[i] = (x == 0.0f) ? -INFINITY : x;
    }
    float m = v[0];
#pragma unroll
    for (int i = 1; i < 16; i++) m = fmaxf(m, v[i]);
#pragma unroll
    for (int off = 32; off; off >>= 1) m = fmaxf(m, __shfl_xor(m, off));
    __shared__ float sm[4];
    __shared__ float ss[4];
    int wid = tid >> 6;
    if ((tid & 63) == 0) sm[wid] = m;
    __syncthreads();
    m = fmaxf(fmaxf(sm[0], sm[1]), fmaxf(sm[2], sm[3]));
    float e[16];
    float s = 0.0f;
#pragma unroll
    for (int i = 0; i < 16; i++) {
        e[i] = __expf(v[i] - m);
        s += e[i];
    }
#pragma unroll
    for (int off = 32; off; off >>= 1) s += __shfl_xor(s, off);
    if ((tid & 63) == 0) ss[wid] = s;
    __syncthreads();
    s = ss[0] + ss[1] + ss[2] + ss[3];
    float inv = 1.0f / s;
    float* S = scores + (size_t)t * BB;
#pragma unroll
    for (int i = 0; i < 16; i++) S[tid + i * 256] = e[i] * inv;
}

// Batched x-side precompute: xc[t][b][:] = gru[b][t][:] @ Wc[0:64][:] + bc.
// Tile: 32 rows x 64 cols per block, 256 threads, 8 outputs/thread.
// X tile staged in LDS padded to 65 (conflict-free column reads),
// Wc1 staged as quads. LDS-broadcast reads amortized over 8 fma each.
__global__ __launch_bounds__(256) void xprep_kernel(
    const float* __restrict__ gru, const float* __restrict__ Wc,
    const float* __restrict__ bc, float* __restrict__ xc) {
    __shared__ float  Xs[32][65];
    __shared__ float4 Ws[1024];     // Wc1 quads: Ws[k*16+q] = Wc[k][4q..4q+3]
    const int tid = threadIdx.x;
    const int n0 = blockIdx.x * 32;
    const int nl = tid >> 3;        // 0..31 row in tile
    const int qs = tid & 7;         // 0..7 quad-pair selector

    const float4* Wq = (const float4*)Wc;   // first 64 rows contiguous
#pragma unroll
    for (int i = 0; i < 4; i++) Ws[tid * 4 + i] = Wq[tid * 4 + i];
    {
        const float4* gq = (const float4*)(gru + (size_t)(n0 + nl) * 64);
        float4 aa = gq[qs * 2];
        float4 bb = gq[qs * 2 + 1];
        float* xrow = &Xs[nl][qs * 8];
        xrow[0] = aa.x; xrow[1] = aa.y; xrow[2] = aa.z; xrow[3] = aa.w;
        xrow[4] = bb.x; xrow[5] = bb.y; xrow[6] = bb.z; xrow[7] = bb.w;
    }
    __syncthreads();

    const float4* bcq = (const float4*)bc;
    float4 acc0 = bcq[qs];
    float4 acc1 = bcq[qs + 8];
#pragma unroll
    for (int k = 0; k < 64; k++) {
        float  xk = Xs[nl][k];
        float4 w0 = Ws[k * 16 + qs];
        float4 w1 = Ws[k * 16 + qs + 8];
        acc0.x = fmaf(xk, w0.x, acc0.x);
        acc0.y = fmaf(xk, w0.y, acc0.y);
        acc0.z = fmaf(xk, w0.z, acc0.z);
        acc0.w = fmaf(xk, w0.w, acc0.w);
        acc1.x = fmaf(xk, w1.x, acc1.x);
        acc1.y = fmaf(xk, w1.y, acc1.y);
        acc1.z = fmaf(xk, w1.z, acc1.z);
        acc1.w = fmaf(xk, w1.w, acc1.w);
    }
    int n = n0 + nl;
    int b = n / 200;
    int t = n - b * 200;
    float4* o = (float4*)(xc + ((size_t)t * BB + b) * 64);
    o[qs]     = acc0;
    o[qs + 8] = acc1;
}

// Consumer-only AUGRU: one 64-lane wave per batch element.
// x-side (xc, xg) precomputed; h broadcast via LDS same-address b128 reads
// (16 ds_read_b128 instead of 64 v_readlane -> ~half the VALU issue/step).
__global__ __launch_bounds__(64, 4) void augru2_kernel(
    const float* __restrict__ xc, const float* __restrict__ xg,
    const float* __restrict__ scores,
    const float* __restrict__ Wu, const float* __restrict__ bu,
    const float* __restrict__ Wr, const float* __restrict__ br,
    const float* __restrict__ Wc, float* __restrict__ out) {
    __shared__ float hbuf[64];
    const int lane = threadIdx.x;
    const int b = blockIdx.x;

    float wc2[64];
#pragma unroll
    for (int k = 0; k < 64; k++) wc2[k] = Wc[(64 + k) * 64 + lane];
    const float wu2l = Wu[64 + lane];
    const float wr2l = Wr[64 + lane];
    const float sbu = bu[0], sbr = br[0];
    const float2* xg2 = (const float2*)xg;

    float h = 0.0f;
    float  xl = xc[(size_t)b * 64 + lane];   // t=0
    float2 g  = xg2[b];
    float  sc = scores[b];

    for (int t = 0; t < TT; t++) {
        // prefetch t+1 (coalesced 256B xc row + uniform scalars)
        float xn = 0.0f, scn = 0.0f;
        float2 gn = make_float2(0.0f, 0.0f);
        if (t + 1 < TT) {
            size_t nidx = (size_t)(t + 1) * BB + b;
            xn  = xc[nidx * 64 + lane];
            gn  = xg2[nidx];
            scn = scores[nidx];
        }

        hbuf[lane] = h;   // same-wave LDS: DS pipe in-order, no barrier needed

        float pu = h * wu2l;
        float pr = h * wr2l;
#pragma unroll
        for (int off = 32; off; off >>= 1) {
            pu += __shfl_xor(pu, off);
            pr += __shfl_xor(pr, off);
        }
        float u = sc / (1.0f + __expf(-(pu + g.x + sbu)));
        float r = 1.0f / (1.0f + __expf(-(pr + g.y + sbr)));

        float a0 = 0.0f, a1 = 0.0f, a2 = 0.0f, a3 = 0.0f;
        const float4* h4 = (const float4*)hbuf;
#pragma unroll
        for (int kq = 0; kq < 16; kq++) {
            float4 hv = h4[kq];   // broadcast read
            a0 = fmaf(hv.x, wc2[4 * kq + 0], a0);
            a1 = fmaf(hv.y, wc2[4 * kq + 1], a1);
            a2 = fmaf(hv.z, wc2[4 * kq + 2], a2);
            a3 = fmaf(hv.w, wc2[4 * kq + 3], a3);
        }
        float arg = xl + r * ((a0 + a1) + (a2 + a3));
        float ex = __expf(2.0f * arg);   // tanh
        float th = 1.0f - 2.0f / (ex + 1.0f);
        h = fmaf(u, th - h, h);

        xl = xn; g = gn; sc = scn;
    }
    out[(size_t)b * 64 + lane] = h;
}

// ---- fallback (small workspace): original fused producer/consumer AUGRU ----
__global__ __launch_bounds__(128, 4) void augru_kernel(
    const float* __restrict__ gru, const float* __restrict__ scores,
    const float* __restrict__ Wu, const float* __restrict__ bu,
    const float* __restrict__ Wr, const float* __restrict__ br,
    const float* __restrict__ Wc, const float* __restrict__ bc,
    float* __restrict__ out) {
    __shared__ float sxc[2][64];
    __shared__ float sxg[2][2];
    const int lane = threadIdx.x & 63;
    const int wid  = threadIdx.x >> 6;
    const int b    = blockIdx.x;
    const float* xrow = gru + (size_t)b * TT * 64;

    if (wid == 0) {
        float wc1[64];
#pragma unroll
        for (int k = 0; k < 64; k++) wc1[k] = Wc[k * 64 + lane];
        float wu1l = Wu[lane], wr1l = Wr[lane];
        float bcl = bc[lane];

        auto produce = [&](int tp, float xl) {
            float pu = xl * wu1l;
            float pr = xl * wr1l;
#pragma unroll
            for (int off = 32; off; off >>= 1) {
                pu += __shfl_xor(pu, off);
                pr += __shfl_xor(pr, off);
            }
            float a0 = bcl, a1 = 0.0f, a2 = 0.0f, a3 = 0.0f;
#pragma unroll
            for (int k = 0; k < 16; k++) {
                a0 = fmaf(lane_bcast(xl, 4 * k + 0), wc1[4 * k + 0], a0);
                a1 = fmaf(lane_bcast(xl, 4 * k + 1), wc1[4 * k + 1], a1);
                a2 = fmaf(lane_bcast(xl, 4 * k + 2), wc1[4 * k + 2], a2);
                a3 = fmaf(lane_bcast(xl, 4 * k + 3), wc1[4 * k + 3], a3);
            }
            int p = tp & 1;
            sxc[p][lane] = (a0 + a1) + (a2 + a3);
            if (lane == 0) sxg[p][0] = pu;
            if (lane == 1) sxg[p][1] = pr;
        };

        float xl = xrow[lane];
        float xn = xrow[64 + lane];
        produce(0, xl);
        xl = xn;
        __syncthreads();
        for (int t = 0; t < TT; t++) {
            if (t + 1 < TT) {
                float xnn = (t + 2 < TT) ? xrow[(size_t)(t + 2) * 64 + lane] : 0.0f;
                produce(t + 1, xl);
                xl = xnn;
            }
            __syncthreads();
        }
    } else {
        float wc2[64];
#pragma unroll
        for (int k = 0; k < 64; k++) wc2[k] = Wc[(64 + k) * 64 + lane];
        float wu2l = Wu[64 + lane], wr2l = Wr[64 + lane];
        float sbu = bu[0], sbr = br[0];
        float h = 0.0f;
        __syncthreads();
        for (int t = 0; t < TT; t++) {
            int p = t & 1;
            float sc = scores[(size_t)t * BB + b];
            float xcv = sxc[p][lane];
            float xu = sxg[p][0];
            float xv = sxg[p][1];
            float pu = h * wu2l;
            float pr = h * wr2l;
#pragma unroll
            for (int off = 32; off; off >>= 1) {
                pu += __shfl_xor(pu, off);
                pr += __shfl_xor(pr, off);
            }
            float u = sc / (1.0f + __expf(-(pu + xu + sbu)));
            float r = 1.0f / (1.0f + __expf(-(pr + xv + sbr)));
            float a0 = 0.0f, a1 = 0.0f, a2 = 0.0f, a3 = 0.0f;
#pragma unroll
            for (int k = 0; k < 16; k++) {
                a0 = fmaf(lane_bcast(h, 4 * k + 0), wc2[4 * k + 0], a0);
                a1 = fmaf(lane_bcast(h, 4 * k + 1), wc2[4 * k + 1], a1);
                a2 = fmaf(lane_bcast(h, 4 * k + 2), wc2[4 * k + 2], a2);
                a3 = fmaf(lane_bcast(h, 4 * k + 3), wc2[4 * k + 3], a3);
            }
            float arg = xcv + r * ((a0 + a1) + (a2 + a3));
            float ex = __expf(2.0f * arg);
            float th = 1.0f - 2.0f / (ex + 1.0f);
            h = fmaf(u, th - h, h);
            __syncthreads();
        }
        out[(size_t)b * 64 + lane] = h;
    }
}

extern "C" void kernel_launch(void* const* d_in, const int* in_sizes, int n_in,
                              void* d_out, int out_size, void* d_ws, size_t ws_size,
                              hipStream_t stream) {
    const float* gru     = (const float*)d_in[0];
    const float* targets = (const float*)d_in[1];
    const float* W1 = (const float*)d_in[2];
    const float* b1 = (const float*)d_in[3];
    const float* W2 = (const float*)d_in[4];
    const float* b2 = (const float*)d_in[5];
    const float* Wf = (const float*)d_in[6];
    const float* bf = (const float*)d_in[7];
    const float* Wu = (const float*)d_in[8];
    const float* bu = (const float*)d_in[9];
    const float* Wr = (const float*)d_in[10];
    const float* br = (const float*)d_in[11];
    const float* Wc = (const float*)d_in[12];
    const float* bc = (const float*)d_in[13];
    float* out = (float*)d_out;

    float* ws     = (float*)d_ws;
    float* logits = ws + 337920;
    float* scores = ws + 1157120;

    const bool big = (ws_size >= WS_NEED_BYTES);
    float* xg = big ? ws + OFF_XG : nullptr;
    float* xc = ws + OFF_XC;

    prep_kernel<<<20, 256, 0, stream>>>(W1, ws);
    qw_kernel<<<1280, 256, 0, stream>>>(targets, b1, ws, ws + 10240);
    mlp_kernel<<<3200, 256, 0, stream>>>(gru, targets, W1, W2, b2, Wf, bf, Wu, Wr,
                                         ws, logits, xg);
    softmax_kernel<<<200, 256, 0, stream>>>(logits, scores);
    if (big) {
        xprep_kernel<<<25600, 256, 0, stream>>>(gru, Wc, bc, xc);
        augru2_kernel<<<4096, 64, 0, stream>>>(xc, xg, scores, Wu, bu, Wr, br, Wc, out);
    } else {
        augru_kernel<<<4096, 128, 0, stream>>>(gru, scores, Wu, bu, Wr, br, Wc, bc, out);
    }
}